// Round 9
// baseline (80.311 us; speedup 1.0000x reference)
//
#include <hip/hip_runtime.h>
#include <hip/hip_bf16.h>

typedef __attribute__((ext_vector_type(8))) short bf16x8;
typedef __attribute__((ext_vector_type(4))) float f32x4;

__device__ __forceinline__ unsigned int pk2(float a, float b) {
  union { __hip_bfloat162 h; unsigned int u; } cv;
  cv.h = __float22bfloat162_rn(make_float2(a, b));   // v_cvt_pk_bf16_f32
  return cv.u;
}
__device__ __forceinline__ unsigned short f2bf(float f) {
  unsigned int u = __float_as_uint(f);
  u += 0x7FFFu + ((u >> 16) & 1u);
  return (unsigned short)(u >> 16);
}

// qw[n][e] = (scale*0.5) * sum_d query[n][d] * W[d][e]; the entmax pre-scale
// (alpha-1)=0.5 is folded in (power-of-2: bit-identical mantissas).
__global__ void __launch_bounds__(256) qw_kernel(const float* __restrict__ q,
                                                 const float* __restrict__ W,
                                                 unsigned short* __restrict__ qw) {
  int n = blockIdx.x, e = threadIdx.x;
  float acc = 0.f;
  #pragma unroll 8
  for (int d = 0; d < 256; ++d) acc = fmaf(q[n * 256 + d], W[d * 256 + e], acc);
  qw[n * 256 + e] = f2bf(acc * 0.03125f);  // 256^-0.5 * 0.5
}

// One block per batch. 512 threads = 8 waves.
// R9: R7 structure + (1) GEMM1/entmax dedup: only waves 0-3 compute att+gate
// (wave-uniform branch; waves 4-7 go straight to the aw barrier);
// (2) GEMM2 B-fragment gathers hoisted before the branch for ALL waves —
// their LDS latency hides under waves 0-3's entmax VALU;
// (3) 0.5 scale folded into qw.
__global__ void __launch_bounds__(512, 6) cross_main(
    const float* __restrict__ x, const float* __restrict__ value,
    const unsigned short* __restrict__ qw, float* __restrict__ out) {

  __shared__ __align__(16) unsigned short lds_x[64 * 268];  // x[f][e] bf16, row = 536 B
  __shared__ __align__(16) unsigned short lds_aw[64 * 72];  // aw[n][f] bf16, row = 144 B

  const int t = threadIdx.x;
  const int b = blockIdx.x;
  const int l = t & 63;
  const int w = t >> 6;
  const int l15 = l & 15, l4 = l >> 4;

  // ---- stage x[b]: 8 loads in flight, then convert+write ----
  {
    const float4* xg = (const float4*)(x + (size_t)b * 16384);
    float4 v[8];
    #pragma unroll
    for (int it = 0; it < 4; ++it) {
      v[2 * it]     = xg[2 * (it * 512 + t)];
      v[2 * it + 1] = xg[2 * (it * 512 + t) + 1];
    }
    #pragma unroll
    for (int it = 0; it < 4; ++it) {
      int u = it * 512 + t;
      int f = u >> 5, c8 = u & 31;
      char* dst = (char*)lds_x + f * 536 + c8 * 16;
      *(uint2*)dst       = make_uint2(pk2(v[2*it].x, v[2*it].y), pk2(v[2*it].z, v[2*it].w));
      *(uint2*)(dst + 8) = make_uint2(pk2(v[2*it+1].x, v[2*it+1].y), pk2(v[2*it+1].z, v[2*it+1].w));
    }
  }
  __syncthreads();          // barrier 1: lds_x ready (stable until kernel end)

  // ---- hoisted GEMM2 B-gathers (depend only on lds_x): all 8 waves ----
  // bb[kc][j]: x^T fragment, e = (2w+j)*16 + l15, f = kc*32 + l4*8 + i
  union BU { unsigned short u[8]; bf16x8 v; };
  BU bb[2][2];
  {
    const int te0 = 2 * w;
    #pragma unroll
    for (int kc = 0; kc < 2; ++kc) {
      const char* gp = (const char*)lds_x + (kc * 32 + l4 * 8) * 536 + (te0 * 16 + l15) * 2;
      #pragma unroll
      for (int j = 0; j < 2; ++j)
        #pragma unroll
        for (int i = 0; i < 8; ++i)
          bb[kc][j].u[i] = *(const unsigned short*)(gp + i * 536 + j * 32);
    }
  }

  // ---- waves 0-3 only: GEMM1 (in-register att) + entmax + aw-write ----
  if (w < 4) {
    const int nt = w;
    f32x4 zz[4];   // f-tile tt: lane holds att[f=16*tt+4*l4+r][n=nt*16+l15]
    #pragma unroll
    for (int tt = 0; tt < 4; ++tt) zz[tt] = (f32x4){0.f, 0.f, 0.f, 0.f};
    {
      const unsigned short* qb = qw + (nt * 16 + l15) * 256 + l4 * 8;
      const char* xa = (const char*)lds_x + l15 * 536 + l4 * 16;
      #pragma unroll
      for (int kc = 0; kc < 8; ++kc) {
        bf16x8 bq = *(const bf16x8*)(qb + kc * 32);   // global, L1-resident
        #pragma unroll
        for (int tt = 0; tt < 4; ++tt) {
          union BF { uint2 d[2]; bf16x8 v; } af;
          const char* p = xa + tt * (16 * 536) + kc * 64;
          af.d[0] = *(const uint2*)p;
          af.d[1] = *(const uint2*)(p + 8);
          zz[tt] = __builtin_amdgcn_mfma_f32_16x16x32_bf16(af.v, bq, zz[tt], 0, 0, 0);
        }
      }
    }
    const int n = nt * 16 + l15;
    float z[16];
    #pragma unroll
    for (int tt = 0; tt < 4; ++tt)
      #pragma unroll
      for (int r = 0; r < 4; ++r) z[tt * 4 + r] = zz[tt][r];   // 0.5 folded into qw

    float m = z[0];
    #pragma unroll
    for (int k = 1; k < 16; ++k) m = fmaxf(m, z[k]);
    m = fmaxf(m, __shfl_xor(m, 16));
    m = fmaxf(m, __shfl_xor(m, 32));

    float tau = m - 1.0f;     // Newton from bracket-lo: monotone from below
    #pragma unroll
    for (int it = 0; it < 12; ++it) {
      float s0 = 0.f, s1 = 0.f, q0 = 0.f, q1 = 0.f;
      #pragma unroll
      for (int k = 0; k < 8; ++k) {
        float d0 = fmaxf(z[k] - tau, 0.f);
        float d1 = fmaxf(z[k + 8] - tau, 0.f);
        s0 = fmaf(d0, d0, s0); q0 += d0;
        s1 = fmaf(d1, d1, s1); q1 += d1;
      }
      float s = s0 + s1, q = q0 + q1;
      s += __shfl_xor(s, 16); s += __shfl_xor(s, 32);
      q += __shfl_xor(q, 16); q += __shfl_xor(q, 32);
      tau += (s - 1.0f) * 0.5f * __builtin_amdgcn_rcpf(q);
    }

    float p[16]; float S = 0.f;
    #pragma unroll
    for (int k = 0; k < 16; ++k) { float d = fmaxf(z[k] - tau, 0.f); p[k] = d * d; S += p[k]; }
    S += __shfl_xor(S, 16); S += __shfl_xor(S, 32);
    float invS = 1.0f / S;

    #pragma unroll
    for (int tt = 0; tt < 4; ++tt) {     // f = 16*tt + 4*l4 + r
      float4 vv = *(const float4*)(value + n * 64 + tt * 16 + l4 * 4);
      uint2 pkd = make_uint2(pk2(p[tt*4] * invS * vv.x,   p[tt*4+1] * invS * vv.y),
                             pk2(p[tt*4+2] * invS * vv.z, p[tt*4+3] * invS * vv.w));
      *(uint2*)&lds_aw[n * 72 + tt * 16 + l4 * 4] = pkd;
    }
  }
  __syncthreads();          // barrier 2: aw ready

  // ---- out[n][e] = exp( sum_f aw[n][f] * x[f][e] ); B-frags already in regs ----
  {
    const int te0 = 2 * w;
    f32x4 acc[4][2];
    #pragma unroll
    for (int nt2 = 0; nt2 < 4; ++nt2) {
      acc[nt2][0] = (f32x4){0.f, 0.f, 0.f, 0.f};
      acc[nt2][1] = (f32x4){0.f, 0.f, 0.f, 0.f};
    }
    #pragma unroll
    for (int kc = 0; kc < 2; ++kc) {
      bf16x8 a[4];
      #pragma unroll
      for (int nt2 = 0; nt2 < 4; ++nt2)
        a[nt2] = *(const bf16x8*)&lds_aw[(nt2 * 16 + l15) * 72 + kc * 32 + l4 * 8];
      #pragma unroll
      for (int j = 0; j < 2; ++j)
        #pragma unroll
        for (int nt2 = 0; nt2 < 4; ++nt2)
          acc[nt2][j] = __builtin_amdgcn_mfma_f32_16x16x32_bf16(a[nt2], bb[kc][j].v, acc[nt2][j], 0, 0, 0);
    }
    float* ob = out + (size_t)b * 16384;
    #pragma unroll
    for (int nt2 = 0; nt2 < 4; ++nt2)
      #pragma unroll
      for (int j = 0; j < 2; ++j)
        #pragma unroll
        for (int r = 0; r < 4; ++r)
          ob[(nt2 * 16 + 4 * l4 + r) * 256 + (te0 + j) * 16 + l15] = __expf(acc[nt2][j][r]);
  }
}

extern "C" void kernel_launch(void* const* d_in, const int* in_sizes, int n_in,
                              void* d_out, int out_size, void* d_ws, size_t ws_size,
                              hipStream_t stream) {
  const float* x     = (const float*)d_in[0];
  const float* W     = (const float*)d_in[1];
  const float* q     = (const float*)d_in[2];
  const float* value = (const float*)d_in[3];
  float* out = (float*)d_out;
  unsigned short* qw = (unsigned short*)d_ws;  // 64*256 bf16 = 32 KB scratch

  qw_kernel<<<dim3(64), dim3(256), 0, stream>>>(q, W, qw);
  cross_main<<<dim3(2048), dim3(512), 0, stream>>>(x, value, qw, out);
}